// Round 1
// baseline (499.536 us; speedup 1.0000x reference)
//
#include <hip/hip_runtime.h>
#include <hip/hip_bf16.h>
#include <stdint.h>

typedef unsigned short u16t;
typedef short s8v __attribute__((ext_vector_type(8)));   // 8 bf16 (MFMA A/B frag)
typedef float f32x4 __attribute__((ext_vector_type(4))); // MFMA C/D frag

// ---- constants for this problem ----
#define BB 4
#define SS 2048
#define DD 1024
#define HH 16
#define HD 64
#define MROWS (BB*SS)          // 8192
#define OUT_ELEMS (MROWS*DD)   // 8388608
#define KV_ELEMS (MROWS*DD)    // 8388608 per of k/v in [B,H,S,hd]

__device__ __forceinline__ u16t f2bf(float f) {
  union { float f; unsigned int u; } v; v.f = f;
  unsigned int u = v.u;
  unsigned int r = (u + 0x7FFFu + ((u >> 16) & 1u)) >> 16;
  return (u16t)r;
}

__device__ __forceinline__ void async_copy16(u16t* lds_dst, const u16t* g_src) {
  __builtin_amdgcn_global_load_lds(
      (const __attribute__((address_space(1))) unsigned int*)(g_src),
      (__attribute__((address_space(3))) unsigned int*)(lds_dst),
      16, 0, 0);
}

// ---------------- conversion kernels ----------------
__global__ void convert_f32_bf16(const float* __restrict__ in, u16t* __restrict__ out) {
  int i = (blockIdx.x * blockDim.x + threadIdx.x) * 4;
  float4 f = *(const float4*)(in + i);
  ushort4 o;
  o.x = f2bf(f.x); o.y = f2bf(f.y); o.z = f2bf(f.z); o.w = f2bf(f.w);
  *(ushort4*)(out + i) = o;
}

// w_proj [K=1024][N=1024] f32 -> WT [N][K] bf16
__global__ void transpose_to_bf16(const float* __restrict__ W, u16t* __restrict__ WT) {
  __shared__ float tile[64][65];
  int bx = blockIdx.x & 15;   // n tile
  int by = blockIdx.x >> 4;   // k tile
  int t = threadIdx.x;
  int c = t & 63, r0 = t >> 6;
  for (int i = 0; i < 16; i++) {
    int r = r0 * 16 + i;
    tile[r][c] = W[(size_t)(by*64 + r)*1024 + bx*64 + c];
  }
  __syncthreads();
  for (int i = 0; i < 16; i++) {
    int r = r0 * 16 + i;
    WT[(size_t)(bx*64 + r)*1024 + by*64 + c] = f2bf(tile[c][r]);
  }
}

// ---------------- GEMM: C[M,N] = A[M,K] * B[N,K]^T + bias ----------------
// MODE 0: QKV epilogue (scatter to q/k/v bf16 [B,H,S,hd] + present f32)
// MODE 1: proj epilogue (f32 out row-major)
template<int MODE>
__global__ __launch_bounds__(256)
void gemm_bt(const u16t* __restrict__ A, const u16t* __restrict__ Bm,
             const float* __restrict__ bias, float* __restrict__ outF,
             u16t* __restrict__ qb, u16t* __restrict__ kb, u16t* __restrict__ vb,
             float* __restrict__ presK, float* __restrict__ presV,
             int M, int N, int K) {
  __shared__ u16t As[128*32];
  __shared__ u16t Bs[128*32];
  int tiles_n = N >> 7;
  int bm = blockIdx.x / tiles_n, bn = blockIdx.x % tiles_n;
  int t = threadIdx.x;
  int w = t >> 6, l = t & 63;
  int wm = (w >> 1) * 64, wn = (w & 1) * 64;
  int lr = l & 15, lg = l >> 4;
  int r4 = l >> 2, c8 = (l & 3) * 8;
  const u16t* Ab = A  + (size_t)(bm * 128) * K;
  const u16t* Bb = Bm + (size_t)(bn * 128) * K;

  f32x4 acc[4][4] = {};

  for (int k0 = 0; k0 < K; k0 += 32) {
    __syncthreads();
    async_copy16(As + w*512,        Ab + (size_t)(w*16 + r4)*K      + k0 + c8);
    async_copy16(As + 2048 + w*512, Ab + (size_t)(64 + w*16 + r4)*K + k0 + c8);
    async_copy16(Bs + w*512,        Bb + (size_t)(w*16 + r4)*K      + k0 + c8);
    async_copy16(Bs + 2048 + w*512, Bb + (size_t)(64 + w*16 + r4)*K + k0 + c8);
    __syncthreads();   // compiler drains vmcnt before barrier
    s8v a[4], b[4];
#pragma unroll
    for (int mf = 0; mf < 4; mf++) a[mf] = *(s8v*)&As[(wm + mf*16 + lr)*32 + lg*8];
#pragma unroll
    for (int nf = 0; nf < 4; nf++) b[nf] = *(s8v*)&Bs[(wn + nf*16 + lr)*32 + lg*8];
#pragma unroll
    for (int mf = 0; mf < 4; mf++)
#pragma unroll
      for (int nf = 0; nf < 4; nf++)
        acc[mf][nf] = __builtin_amdgcn_mfma_f32_16x16x32_bf16(a[mf], b[nf], acc[mf][nf], 0, 0, 0);
  }

#pragma unroll
  for (int mf = 0; mf < 4; mf++)
#pragma unroll
    for (int nf = 0; nf < 4; nf++)
#pragma unroll
      for (int j = 0; j < 4; j++) {
        int m = bm*128 + wm + mf*16 + lg*4 + j;
        int n = bn*128 + wn + nf*16 + lr;
        float val = acc[mf][nf][j] + bias[n];
        if (MODE == 1) {
          outF[(size_t)m * N + n] = val;
        } else {
          int part = n >> 10, nn = n & 1023;
          int h = nn >> 6, d = nn & 63;
          int bi = m >> 11, s = m & 2047;
          size_t idx = ((size_t)(bi*HH + h)*SS + s)*HD + d;
          if (part == 0) {
            qb[idx] = f2bf(val * 0.125f);          // fold 1/sqrt(hd) into q
          } else if (part == 1) {
            kb[idx] = f2bf(val); presK[idx] = val;
          } else {
            vb[idx] = f2bf(val); presV[idx] = val;
          }
        }
      }
}

// ---------------- causal flash attention ----------------
// grid = (B*H) * (S/64); block 256 (4 waves x 16 q-rows)
__global__ __launch_bounds__(256)
void attn_kernel(const u16t* __restrict__ qb, const u16t* __restrict__ kb,
                 const u16t* __restrict__ vb, u16t* __restrict__ ab) {
  __shared__ u16t Qs[64*72];
  __shared__ u16t Ks[64*72];
  __shared__ u16t Vt[64*72];
  __shared__ u16t Ps[4*16*72];
  int bh = blockIdx.x >> 5;
  int q0 = (blockIdx.x & 31) * 64;
  int t = threadIdx.x, w = t >> 6, l = t & 63;
  int lr = l & 15, lg = l >> 4;
  const u16t* Qg = qb + (size_t)bh * SS * HD;
  const u16t* Kg = kb + (size_t)bh * SS * HD;
  const u16t* Vg = vb + (size_t)bh * SS * HD;

  {
    int r = t >> 2, c = (t & 3) * 16;
    *(s8v*)&Qs[r*72 + c]     = *(const s8v*)&Qg[(size_t)(q0 + r)*HD + c];
    *(s8v*)&Qs[r*72 + c + 8] = *(const s8v*)&Qg[(size_t)(q0 + r)*HD + c + 8];
  }
  __syncthreads();
  s8v qa0 = *(s8v*)&Qs[(w*16 + lr)*72 + lg*8];
  s8v qa1 = *(s8v*)&Qs[(w*16 + lr)*72 + 32 + lg*8];

  f32x4 o[4] = {};
  float mrow[4], lrow[4];
#pragma unroll
  for (int j = 0; j < 4; j++) { mrow[j] = -1e30f; lrow[j] = 0.f; }

  int ntiles = q0/64 + 1;
  for (int tt = 0; tt < ntiles; tt++) {
    int kv0 = tt * 64;
    __syncthreads();
    {
      int r = t >> 2, c = (t & 3) * 16;
      *(s8v*)&Ks[r*72 + c]     = *(const s8v*)&Kg[(size_t)(kv0 + r)*HD + c];
      *(s8v*)&Ks[r*72 + c + 8] = *(const s8v*)&Kg[(size_t)(kv0 + r)*HD + c + 8];
      s8v v0 = *(const s8v*)&Vg[(size_t)(kv0 + r)*HD + c];
      s8v v1 = *(const s8v*)&Vg[(size_t)(kv0 + r)*HD + c + 8];
#pragma unroll
      for (int i = 0; i < 8; i++) Vt[(c + i)*72 + r]     = (u16t)v0[i];
#pragma unroll
      for (int i = 0; i < 8; i++) Vt[(c + i + 8)*72 + r] = (u16t)v1[i];
    }
    __syncthreads();

    f32x4 s[4];
#pragma unroll
    for (int nf = 0; nf < 4; nf++) {
      s8v bk0 = *(s8v*)&Ks[(nf*16 + lr)*72 + lg*8];
      s8v bk1 = *(s8v*)&Ks[(nf*16 + lr)*72 + 32 + lg*8];
      f32x4 a = {};
      a = __builtin_amdgcn_mfma_f32_16x16x32_bf16(qa0, bk0, a, 0, 0, 0);
      a = __builtin_amdgcn_mfma_f32_16x16x32_bf16(qa1, bk1, a, 0, 0, 0);
      s[nf] = a;
    }
    if (kv0 == q0) {  // diagonal tile: causal mask
#pragma unroll
      for (int nf = 0; nf < 4; nf++)
#pragma unroll
        for (int j = 0; j < 4; j++) {
          int row = w*16 + lg*4 + j;
          int col = nf*16 + lr;
          if (col > row) s[nf][j] = -1e30f;
        }
    }
    float resc[4];
#pragma unroll
    for (int j = 0; j < 4; j++) {
      float mx = fmaxf(fmaxf(s[0][j], s[1][j]), fmaxf(s[2][j], s[3][j]));
      mx = fmaxf(mx, __shfl_xor(mx, 1));
      mx = fmaxf(mx, __shfl_xor(mx, 2));
      mx = fmaxf(mx, __shfl_xor(mx, 4));
      mx = fmaxf(mx, __shfl_xor(mx, 8));
      float mnew = fmaxf(mrow[j], mx);
      float sum = 0.f;
#pragma unroll
      for (int nf = 0; nf < 4; nf++) {
        float p = __expf(s[nf][j] - mnew);
        s[nf][j] = p;
        sum += p;
      }
      sum += __shfl_xor(sum, 1);
      sum += __shfl_xor(sum, 2);
      sum += __shfl_xor(sum, 4);
      sum += __shfl_xor(sum, 8);
      float r = __expf(mrow[j] - mnew);
      lrow[j] = lrow[j]*r + sum;
      mrow[j] = mnew;
      resc[j] = r;
    }
#pragma unroll
    for (int nf = 0; nf < 4; nf++)
#pragma unroll
      for (int j = 0; j < 4; j++) o[nf][j] *= resc[j];

    u16t* Pw = &Ps[w*16*72];
#pragma unroll
    for (int nf = 0; nf < 4; nf++)
#pragma unroll
      for (int j = 0; j < 4; j++)
        Pw[(lg*4 + j)*72 + nf*16 + lr] = f2bf(s[nf][j]);
    // per-wave LDS region; same-wave DS ordering + compiler dep tracking
    s8v pa0 = *(s8v*)&Pw[lr*72 + lg*8];
    s8v pa1 = *(s8v*)&Pw[lr*72 + 32 + lg*8];
#pragma unroll
    for (int nf = 0; nf < 4; nf++) {
      s8v vb0 = *(s8v*)&Vt[(nf*16 + lr)*72 + lg*8];
      s8v vb1 = *(s8v*)&Vt[(nf*16 + lr)*72 + 32 + lg*8];
      o[nf] = __builtin_amdgcn_mfma_f32_16x16x32_bf16(pa0, vb0, o[nf], 0, 0, 0);
      o[nf] = __builtin_amdgcn_mfma_f32_16x16x32_bf16(pa1, vb1, o[nf], 0, 0, 0);
    }
  }

  int bi = bh >> 4, h = bh & 15;
#pragma unroll
  for (int nf = 0; nf < 4; nf++)
#pragma unroll
    for (int j = 0; j < 4; j++) {
      int row = q0 + w*16 + lg*4 + j;
      int col = h*HD + nf*16 + lr;
      float val = o[nf][j] / lrow[j];
      ab[((size_t)bi*SS + row)*DD + col] = f2bf(val);
    }
}

extern "C" void kernel_launch(void* const* d_in, const int* in_sizes, int n_in,
                              void* d_out, int out_size, void* d_ws, size_t ws_size,
                              hipStream_t stream) {
  const float* x      = (const float*)d_in[0];
  const float* w_attn = (const float*)d_in[1];
  const float* b_attn = (const float*)d_in[2];
  const float* w_proj = (const float*)d_in[3];
  const float* b_proj = (const float*)d_in[4];
  float* out   = (float*)d_out;
  float* presK = out + (size_t)OUT_ELEMS;
  float* presV = presK + (size_t)KV_ELEMS;

  u16t* ws    = (u16t*)d_ws;
  u16t* x_bf  = ws;                        // 8388608 elems
  u16t* wa_bf = x_bf  + (size_t)OUT_ELEMS; // 3145728
  u16t* wpT   = wa_bf + 3145728;           // 1048576
  u16t* q_bf  = wpT   + 1048576;           // 8388608
  u16t* k_bf  = q_bf  + (size_t)KV_ELEMS;
  u16t* v_bf  = k_bf  + (size_t)KV_ELEMS;
  u16t* a_bf  = x_bf;                      // reuse x_bf after QKV GEMM

  convert_f32_bf16<<<8192, 256, 0, stream>>>(x, x_bf);
  convert_f32_bf16<<<3072, 256, 0, stream>>>(w_attn, wa_bf);
  transpose_to_bf16<<<256, 256, 0, stream>>>(w_proj, wpT);

  gemm_bt<0><<<64*24, 256, 0, stream>>>(x_bf, wa_bf, b_attn, nullptr,
                                        q_bf, k_bf, v_bf, presK, presV,
                                        MROWS, 3*DD, DD);
  attn_kernel<<<64*32, 256, 0, stream>>>(q_bf, k_bf, v_bf, a_bf);
  gemm_bt<1><<<64*8, 256, 0, stream>>>(a_bf, wpT, b_proj, out,
                                       nullptr, nullptr, nullptr, nullptr, nullptr,
                                       MROWS, DD, DD);
}